// Round 1
// baseline (473.690 us; speedup 1.0000x reference)
//
#include <hip/hip_runtime.h>
#include <hip/hip_fp16.h>

typedef _Float16 f16;
typedef _Float16 f16x8 __attribute__((ext_vector_type(8)));
typedef float f32x4 __attribute__((ext_vector_type(4)));

#define BB 4
#define TT 16
#define HH 64
#define WW 64
#define CC 32
#define FF 64
#define GG 256  // 4F gates

__device__ __forceinline__ float hsig(float z) {
    return fminf(fmaxf(0.2f * z + 0.5f, 0.f), 1.f);
}
__device__ __forceinline__ float tanh_fast(float x) {
    // 1 - 2/(e^{2x}+1); saturates correctly at +-inf
    return 1.f - 2.f / (__expf(2.f * x) + 1.f);
}

// ---------------- LayerNorm over C=32: fp32 in -> fp16 out ----------------
__global__ void ln_kernel(const float* __restrict__ x,
                          const float* __restrict__ gamma,
                          const float* __restrict__ beta,
                          f16* __restrict__ xn) {
    __shared__ float sg[CC], sb[CC];
    if (threadIdx.x < CC) sg[threadIdx.x] = gamma[threadIdx.x];
    else if (threadIdx.x < 2 * CC) sb[threadIdx.x - CC] = beta[threadIdx.x - CC];
    __syncthreads();
    int q = blockIdx.x * 256 + threadIdx.x;  // pixel < B*T*H*W = 262144
    const float* xp = x + (size_t)q * CC;
    float v[CC];
    float s = 0.f, s2 = 0.f;
#pragma unroll
    for (int c = 0; c < CC; c += 4) {
        float4 t4 = *(const float4*)(xp + c);
        v[c] = t4.x; v[c + 1] = t4.y; v[c + 2] = t4.z; v[c + 3] = t4.w;
        s += t4.x + t4.y + t4.z + t4.w;
        s2 += t4.x * t4.x + t4.y * t4.y + t4.z * t4.z + t4.w * t4.w;
    }
    float mu = s * (1.f / CC);
    float var = s2 * (1.f / CC) - mu * mu;
    float rs = rsqrtf(var + 1e-3f);
    f16 o[CC];
#pragma unroll
    for (int c = 0; c < CC; c++)
        o[c] = (f16)((v[c] - mu) * rs * sg[c] + sb[c]);
    f16x8* d = (f16x8*)(xn + (size_t)q * CC);
#pragma unroll
    for (int c = 0; c < 4; c++) d[c] = *(f16x8*)&o[c * 8];
}

// ------- Weight transpose to N-major [n][k] fp16 (k contiguous for B-frags) -------
__global__ void wprep_kernel(const float* __restrict__ wx, const float* __restrict__ wh,
                             f16* __restrict__ wxt, f16* __restrict__ wht) {
    int e = blockIdx.x * 256 + threadIdx.x;
    if (e < 9 * CC * GG) {                    // 73728: Wx [tap][c][n] -> [n][tap*32+c]
        int n = e & 255, k = e >> 8;          // k in [0,288)
        wxt[n * 288 + k] = (f16)wx[e];
    } else {
        e -= 9 * CC * GG;
        if (e < 9 * FF * GG) {                // 147456: Wh [tap][f][n] -> [n][tap*64+f]
            int n = e & 255, k = e >> 8;      // k in [0,576)
            wht[n * 576 + k] = (f16)wh[e];
        }
    }
}

// ---------------- Fused conv(x)+conv(h)+gates+state step ----------------
// Grid: 512 = 256 tiles (B x H/8 x W/8) x 2 gate-halves. Block: 128 (2 waves).
// Wave w: 4 M-tiles (64 px) x 4 N-tiles (16 gates per class), acc 4x4x4 = 64 VGPR.
__global__ __launch_bounds__(128)
void step_kernel(const f16* __restrict__ xn, const f16* __restrict__ wxt,
                 const f16* __restrict__ wht, const float* __restrict__ bs,
                 float* __restrict__ cst, f16* __restrict__ hs, int t) {
    __shared__ f16 xpatch[10 * 10 * CC];  // 6.4 KB
    __shared__ f16 hpatch[10 * 10 * FF];  // 12.8 KB
    __shared__ f16 bstage[128 * 32];      // 8 KB

    int tile = blockIdx.x >> 1;
    int nhalf = blockIdx.x & 1;
    int bb = tile >> 6, ty = (tile >> 3) & 7, tx = tile & 7;
    int tid = threadIdx.x;
    int lane = tid & 63, w = tid >> 6;
    int quad = lane >> 4, noff = lane & 15;

    const f16* xslice = xn + (size_t)(bb * TT + t) * (HH * WW) * CC;
    const f16* hprev = hs + (size_t)t * (BB * HH * WW * FF);
    f16* hnew = hs + (size_t)(t + 1) * (BB * HH * WW * FF);

    // x patch: 100 pixels x 32ch, zero-padded borders
    if (tid < 100) {
        int py = tid / 10, px = tid % 10;
        int y = ty * 8 - 1 + py, x = tx * 8 - 1 + px;
        f16x8* d = (f16x8*)&xpatch[tid * CC];
        if (y >= 0 && y < HH && x >= 0 && x < WW) {
            const f16x8* s = (const f16x8*)(xslice + ((size_t)y * WW + x) * CC);
            d[0] = s[0]; d[1] = s[1]; d[2] = s[2]; d[3] = s[3];
        } else {
            f16x8 z = {(f16)0, (f16)0, (f16)0, (f16)0, (f16)0, (f16)0, (f16)0, (f16)0};
            d[0] = z; d[1] = z; d[2] = z; d[3] = z;
        }
    }
    // h patch: 100 pixels x 64ch (200 half-rows of 32)
    for (int j = tid; j < 200; j += 128) {
        int pix = j >> 1, hh2 = j & 1;
        int py = pix / 10, px = pix % 10;
        int y = ty * 8 - 1 + py, x = tx * 8 - 1 + px;
        f16x8* d = (f16x8*)&hpatch[pix * FF + hh2 * 32];
        if (y >= 0 && y < HH && x >= 0 && x < WW) {
            const f16x8* s = (const f16x8*)(hprev + ((size_t)(bb * HH + y) * WW + x) * FF + hh2 * 32);
            d[0] = s[0]; d[1] = s[1]; d[2] = s[2]; d[3] = s[3];
        } else {
            f16x8 z = {(f16)0, (f16)0, (f16)0, (f16)0, (f16)0, (f16)0, (f16)0, (f16)0};
            d[0] = z; d[1] = z; d[2] = z; d[3] = z;
        }
    }

    f32x4 acc[4][4];
#pragma unroll
    for (int i = 0; i < 4; i++)
#pragma unroll
        for (int j = 0; j < 4; j++) acc[i][j] = (f32x4){0.f, 0.f, 0.f, 0.f};

    // ---- x-conv: 9 taps x 32ch (K chunks of 32) ----
#pragma unroll 3
    for (int tap = 0; tap < 9; tap++) {
        __syncthreads();  // bstage free + (first iter) patches ready
        if (tid < 128) {
            int gg = tid >> 5, u = tid & 31;
            int n = (gg << 6) + (nhalf << 5) + u;
            const f16x8* s = (const f16x8*)(wxt + (size_t)n * 288 + tap * 32);
            f16x8* d = (f16x8*)&bstage[tid << 5];
            d[0] = s[0]; d[1] = s[1]; d[2] = s[2]; d[3] = s[3];
        }
        __syncthreads();
        int dy = tap / 3, dx = tap % 3;
        f16x8 a[4];
#pragma unroll
        for (int mt = 0; mt < 4; mt++) {
            int m = mt * 16 + noff;
            a[mt] = *(const f16x8*)&xpatch[(((m >> 3) + dy) * 10 + (m & 7) + dx) * CC + (quad << 3)];
        }
#pragma unroll
        for (int gg = 0; gg < 4; gg++) {
            f16x8 bfrag = *(const f16x8*)&bstage[(((gg << 5) + (w << 4) + noff) << 5) + (quad << 3)];
#pragma unroll
            for (int mt = 0; mt < 4; mt++)
                acc[mt][gg] = __builtin_amdgcn_mfma_f32_16x16x32_f16(a[mt], bfrag, acc[mt][gg], 0, 0, 0);
        }
    }

    // ---- h-conv: 9 taps x 64ch (18 K chunks of 32) ----
#pragma unroll 2
    for (int hc = 0; hc < 18; hc++) {
        int tap = hc >> 1, coff = (hc & 1) << 5;
        __syncthreads();
        if (tid < 128) {
            int gg = tid >> 5, u = tid & 31;
            int n = (gg << 6) + (nhalf << 5) + u;
            const f16x8* s = (const f16x8*)(wht + (size_t)n * 576 + tap * 64 + coff);
            f16x8* d = (f16x8*)&bstage[tid << 5];
            d[0] = s[0]; d[1] = s[1]; d[2] = s[2]; d[3] = s[3];
        }
        __syncthreads();
        int dy = tap / 3, dx = tap % 3;
        f16x8 a[4];
#pragma unroll
        for (int mt = 0; mt < 4; mt++) {
            int m = mt * 16 + noff;
            a[mt] = *(const f16x8*)&hpatch[(((m >> 3) + dy) * 10 + (m & 7) + dx) * FF + coff + (quad << 3)];
        }
#pragma unroll
        for (int gg = 0; gg < 4; gg++) {
            f16x8 bfrag = *(const f16x8*)&bstage[(((gg << 5) + (w << 4) + noff) << 5) + (quad << 3)];
#pragma unroll
            for (int mt = 0; mt < 4; mt++)
                acc[mt][gg] = __builtin_amdgcn_mfma_f32_16x16x32_f16(a[mt], bfrag, acc[mt][gg], 0, 0, 0);
        }
    }

    // ---- epilogue: gates + state update (pure per-lane register math) ----
    // lane covers gate f = nhalf*32 + w*16 + noff; acc[mt][gg] = gate class gg (i,f,c,o)
    int f = (nhalf << 5) + (w << 4) + noff;
    float b_i = bs[f], b_f = bs[64 + f], b_c = bs[128 + f], b_o = bs[192 + f];
#pragma unroll
    for (int mt = 0; mt < 4; mt++) {
#pragma unroll
        for (int r = 0; r < 4; r++) {
            int m = mt * 16 + (quad << 2) + r;  // C/D row = quad*4+reg
            int y = ty * 8 + (m >> 3), x = tx * 8 + (m & 7);
            size_t p = (size_t)(bb * HH + y) * WW + x;
            float zi = acc[mt][0][r] + b_i;
            float zf = acc[mt][1][r] + b_f;
            float zc = acc[mt][2][r] + b_c;
            float zo = acc[mt][3][r] + b_o;
            float ig = hsig(zi), fg = hsig(zf), og = hsig(zo);
            float cold = cst[p * FF + f];
            float cn = fg * cold + ig * tanh_fast(zc);
            cst[p * FF + f] = cn;
            hnew[p * FF + f] = (f16)(og * tanh_fast(cn));
        }
    }
}

// ---------------- MaxPool 2x2 over h history -> fp32 out ----------------
__global__ void pool_kernel(const f16* __restrict__ hs, float* __restrict__ out) {
    int idx = blockIdx.x * 256 + threadIdx.x;  // < 4,194,304
    int f = idx & 63;
    int ox = (idx >> 6) & 31;
    int oy = (idx >> 11) & 31;
    int t = (idx >> 16) & 15;
    int bb = idx >> 20;
    const f16* base = hs + (size_t)(t + 1) * (BB * HH * WW * FF)
                    + ((size_t)(bb * HH + oy * 2) * WW + ox * 2) * FF + f;
    float v0 = (float)base[0];
    float v1 = (float)base[FF];
    float v2 = (float)base[WW * FF];
    float v3 = (float)base[WW * FF + FF];
    out[idx] = fmaxf(fmaxf(v0, v1), fmaxf(v2, v3));
}

extern "C" void kernel_launch(void* const* d_in, const int* in_sizes, int n_in,
                              void* d_out, int out_size, void* d_ws, size_t ws_size,
                              hipStream_t stream) {
    const float* x = (const float*)d_in[0];
    const float* gamma = (const float*)d_in[1];
    const float* beta = (const float*)d_in[2];
    const float* wx = (const float*)d_in[3];
    const float* wh = (const float*)d_in[4];
    const float* bs = (const float*)d_in[5];
    float* out = (float*)d_out;

    // workspace layout (all 16B-aligned)
    char* ws = (char*)d_ws;
    f16* xn = (f16*)ws;                                        // 16,777,216 B
    f16* wxt = (f16*)(ws + 16777216);                          //    147,456 B
    f16* wht = (f16*)(ws + 16777216 + 147456);                 //    294,912 B
    float* cst = (float*)(ws + 16777216 + 147456 + 294912);    //  4,194,304 B
    f16* hs = (f16*)(ws + 16777216 + 147456 + 294912 + 4194304);  // 17 x 2,097,152 B
    // total ~57.1 MB

    hipMemsetAsync(cst, 0, (size_t)BB * HH * WW * FF * 4, stream);       // c0 = 0
    hipMemsetAsync(hs, 0, (size_t)BB * HH * WW * FF * 2, stream);        // h0 = 0 (slot 0)

    ln_kernel<<<1024, 256, 0, stream>>>(x, gamma, beta, xn);
    wprep_kernel<<<864, 256, 0, stream>>>(wx, wh, wxt, wht);
    for (int t = 0; t < TT; t++)
        step_kernel<<<512, 128, 0, stream>>>(xn, wxt, wht, bs, cst, hs, t);
    pool_kernel<<<16384, 256, 0, stream>>>(hs, out);
}

// Round 2
// 443.664 us; speedup vs baseline: 1.0677x; 1.0677x over previous
//
#include <hip/hip_runtime.h>
#include <hip/hip_fp16.h>

typedef _Float16 f16;
typedef _Float16 f16x8 __attribute__((ext_vector_type(8)));
typedef float f32x4 __attribute__((ext_vector_type(4)));

#define BB 4
#define TT 16
#define HH 64
#define WW 64
#define CC 32
#define FF 64
#define GG 256  // 4F gates

__device__ __forceinline__ float hsig(float z) {
    return fminf(fmaxf(0.2f * z + 0.5f, 0.f), 1.f);
}
__device__ __forceinline__ float tanh_fast(float x) {
    return 1.f - 2.f / (__expf(2.f * x) + 1.f);
}

// ---------------- LayerNorm over C=32: fp32 in -> fp16 out ----------------
__global__ void ln_kernel(const float* __restrict__ x,
                          const float* __restrict__ gamma,
                          const float* __restrict__ beta,
                          f16* __restrict__ xn) {
    __shared__ float sg[CC], sb[CC];
    if (threadIdx.x < CC) sg[threadIdx.x] = gamma[threadIdx.x];
    else if (threadIdx.x < 2 * CC) sb[threadIdx.x - CC] = beta[threadIdx.x - CC];
    __syncthreads();
    int q = blockIdx.x * 256 + threadIdx.x;  // pixel < B*T*H*W = 262144
    const float* xp = x + (size_t)q * CC;
    float v[CC];
    float s = 0.f, s2 = 0.f;
#pragma unroll
    for (int c = 0; c < CC; c += 4) {
        float4 t4 = *(const float4*)(xp + c);
        v[c] = t4.x; v[c + 1] = t4.y; v[c + 2] = t4.z; v[c + 3] = t4.w;
        s += t4.x + t4.y + t4.z + t4.w;
        s2 += t4.x * t4.x + t4.y * t4.y + t4.z * t4.z + t4.w * t4.w;
    }
    float mu = s * (1.f / CC);
    float var = s2 * (1.f / CC) - mu * mu;
    float rs = rsqrtf(var + 1e-3f);
    f16 o[CC];
#pragma unroll
    for (int c = 0; c < CC; c++)
        o[c] = (f16)((v[c] - mu) * rs * sg[c] + sb[c]);
    f16x8* d = (f16x8*)(xn + (size_t)q * CC);
#pragma unroll
    for (int c = 0; c < 4; c++) d[c] = *(f16x8*)&o[c * 8];
}

// ------- Weight transpose to N-major [n][k] fp16 (k contiguous for B-frags) -------
__global__ void wprep_kernel(const float* __restrict__ wx, const float* __restrict__ wh,
                             f16* __restrict__ wxt, f16* __restrict__ wht) {
    int e = blockIdx.x * 256 + threadIdx.x;
    if (e < 9 * CC * GG) {                    // 73728: Wx [tap][c][n] -> [n][tap*32+c]
        int n = e & 255, k = e >> 8;          // k in [0,288)
        wxt[n * 288 + k] = (f16)wx[e];
    } else {
        e -= 9 * CC * GG;
        if (e < 9 * FF * GG) {                // 147456: Wh [tap][f][n] -> [n][tap*64+f]
            int n = e & 255, k = e >> 8;      // k in [0,576)
            wht[n * 576 + k] = (f16)wh[e];
        }
    }
}

// ---------------- Batched input conv: zx = conv(xn, Wx) + b, all T at once ----------------
// Grid: 8192 = (B*T)(64) x (H/8)(8) x (W/8)(8) tiles x 2 gate-halves. Block: 256 (4 waves).
// Wave (wm,wn): 32 px x 64 gates (16 channels x 4 classes). acc[2][4].
__global__ __launch_bounds__(256, 4)
void zx_kernel(const f16* __restrict__ xn, const f16* __restrict__ wxt,
               const float* __restrict__ bias, f16* __restrict__ zx) {
    // union: loop phase = xpatch(100x40) + bstage(128x40) = 9120 f16;
    //        repack phase = zstage 64px x 168 f16 = 10752 f16
    __shared__ __align__(16) f16 smem[10752];
    f16* xpatch = smem;              // pixel stride 40 (pad: 2-way banks)
    f16* bstage = smem + 4000;       // row stride 40
    f16* zstage = smem;              // pixel stride 168, class stride 40

    int tile = blockIdx.x >> 1, nhalf = blockIdx.x & 1;
    int bt = tile >> 6, ty = (tile >> 3) & 7, tx = tile & 7;
    int tid = threadIdx.x;
    int lane = tid & 63, w = tid >> 6;
    int wm = w >> 1, wn = w & 1;
    int quad = lane >> 4, noff = lane & 15;

    const f16* xslice = xn + (size_t)bt * (HH * WW) * CC;

    // xpatch: 100 px x 32 ch, zero-padded borders, 2 half-rows/thread-pair
    if (tid < 200) {
        int pix = tid >> 1, part = tid & 1;
        int py = pix / 10, px = pix % 10;
        int y = ty * 8 - 1 + py, x = tx * 8 - 1 + px;
        f16x8* d = (f16x8*)&xpatch[pix * 40 + part * 16];
        if (y >= 0 && y < HH && x >= 0 && x < WW) {
            const f16x8* s = (const f16x8*)(xslice + ((size_t)y * WW + x) * CC + part * 16);
            d[0] = s[0]; d[1] = s[1];
        } else {
            f16x8 z = {0, 0, 0, 0, 0, 0, 0, 0};
            d[0] = z; d[1] = z;
        }
    }

    f32x4 acc[2][4];
#pragma unroll
    for (int i = 0; i < 2; i++)
#pragma unroll
        for (int j = 0; j < 4; j++) acc[i][j] = (f32x4){0.f, 0.f, 0.f, 0.f};

    // staging map: row = cls*32 + ch32  <->  global gate g = cls*64 + nhalf*32 + ch32
    int srow = tid >> 1, spart = tid & 1;
    int sg = (srow >> 5) * 64 + nhalf * 32 + (srow & 31);
    const f16* wbase = wxt + (size_t)sg * 288 + spart * 16;
    f16* sdst = &bstage[srow * 40 + spart * 16];

    for (int tap = 0; tap < 9; tap++) {
        __syncthreads();
        {
            const f16x8* s = (const f16x8*)(wbase + tap * 32);
            f16x8* d = (f16x8*)sdst;
            d[0] = s[0]; d[1] = s[1];
        }
        __syncthreads();
        int dy = tap / 3, dx = tap % 3;
        f16x8 a[2];
#pragma unroll
        for (int mt = 0; mt < 2; mt++) {
            int m = wm * 32 + mt * 16 + noff;
            int pp = ((m >> 3) + dy) * 10 + (m & 7) + dx;
            a[mt] = *(const f16x8*)&xpatch[pp * 40 + (quad << 3)];
        }
#pragma unroll
        for (int cls = 0; cls < 4; cls++) {
            int brow = cls * 32 + wn * 16 + noff;
            f16x8 bf = *(const f16x8*)&bstage[brow * 40 + (quad << 3)];
#pragma unroll
            for (int mt = 0; mt < 2; mt++)
                acc[mt][cls] = __builtin_amdgcn_mfma_f32_16x16x32_f16(a[mt], bf, acc[mt][cls], 0, 0, 0);
        }
    }

    // ---- epilogue: + bias, repack through LDS for coalesced 64B stores ----
    int ch32 = wn * 16 + noff;
    float zb[4];
#pragma unroll
    for (int cls = 0; cls < 4; cls++) zb[cls] = bias[cls * 64 + nhalf * 32 + ch32];

    __syncthreads();  // loop-phase smem reads done
#pragma unroll
    for (int mt = 0; mt < 2; mt++)
#pragma unroll
        for (int r = 0; r < 4; r++) {
            int m = wm * 32 + mt * 16 + (quad << 2) + r;  // C/D row = quad*4+reg
#pragma unroll
            for (int cls = 0; cls < 4; cls++)
                zstage[m * 168 + cls * 40 + ch32] = (f16)(acc[mt][cls][r] + zb[cls]);
        }
    __syncthreads();

    // tid -> (pix, cls): write 32 f16 = 64B contiguous to zx
    {
        int pix = tid >> 2, cls = tid & 3;
        int y = ty * 8 + (pix >> 3), x = tx * 8 + (pix & 7);
        const f16x8* s = (const f16x8*)&zstage[pix * 168 + cls * 40];
        f16x8* d = (f16x8*)(zx + ((size_t)bt * (HH * WW) + y * WW + x) * GG + cls * 64 + nhalf * 32);
        d[0] = s[0]; d[1] = s[1]; d[2] = s[2]; d[3] = s[3];
    }
}

// ---------------- Recurrent step: z = zx + conv(h, Wh); gates; state ----------------
// Grid: 512 = 256 px-tiles x 2 gate-halves. Block: 256 (4 waves) -> 2 blocks/CU, 4 waves/SIMD.
__global__ __launch_bounds__(256, 4)
void step_kernel(const f16* __restrict__ zx, const f16* __restrict__ wht,
                 float* __restrict__ cst, f16* __restrict__ hs, int t) {
    __shared__ __align__(16) f16 hpatch[100 * 72];  // 14.4 KB, pixel stride 72 (2-way banks)
    __shared__ __align__(16) f16 bstage[128 * 40];  // 10 KB, row stride 40

    int tile = blockIdx.x >> 1, nhalf = blockIdx.x & 1;
    int bb = tile >> 6, ty = (tile >> 3) & 7, tx = tile & 7;
    int tid = threadIdx.x;
    int lane = tid & 63, w = tid >> 6;
    int wm = w >> 1, wn = w & 1;
    int quad = lane >> 4, noff = lane & 15;

    const f16* hprev = hs + (size_t)t * (BB * HH * WW * FF);
    f16* hnew = hs + (size_t)(t + 1) * (BB * HH * WW * FF);

    // hpatch: 100 px x 64 ch, zero-padded borders
    if (tid < 200) {
        int pix = tid >> 1, half = tid & 1;
        int py = pix / 10, px = pix % 10;
        int y = ty * 8 - 1 + py, x = tx * 8 - 1 + px;
        f16x8* d = (f16x8*)&hpatch[pix * 72 + half * 32];
        if (y >= 0 && y < HH && x >= 0 && x < WW) {
            const f16x8* s = (const f16x8*)(hprev + ((size_t)(bb * HH + y) * WW + x) * FF + half * 32);
            d[0] = s[0]; d[1] = s[1]; d[2] = s[2]; d[3] = s[3];
        } else {
            f16x8 z = {0, 0, 0, 0, 0, 0, 0, 0};
            d[0] = z; d[1] = z; d[2] = z; d[3] = z;
        }
    }

    f32x4 acc[2][4];
#pragma unroll
    for (int i = 0; i < 2; i++)
#pragma unroll
        for (int j = 0; j < 4; j++) acc[i][j] = (f32x4){0.f, 0.f, 0.f, 0.f};

    int srow = tid >> 1, spart = tid & 1;
    int sg = (srow >> 5) * 64 + nhalf * 32 + (srow & 31);
    const f16* wbase = wht + (size_t)sg * 576 + spart * 16;
    f16* sdst = &bstage[srow * 40 + spart * 16];

    for (int hc = 0; hc < 18; hc++) {
        int tap = hc >> 1, coff = (hc & 1) << 5;
        __syncthreads();
        {
            const f16x8* s = (const f16x8*)(wbase + tap * 64 + coff);
            f16x8* d = (f16x8*)sdst;
            d[0] = s[0]; d[1] = s[1];
        }
        __syncthreads();
        int dy = tap / 3, dx = tap % 3;
        f16x8 a[2];
#pragma unroll
        for (int mt = 0; mt < 2; mt++) {
            int m = wm * 32 + mt * 16 + noff;
            int pp = ((m >> 3) + dy) * 10 + (m & 7) + dx;
            a[mt] = *(const f16x8*)&hpatch[pp * 72 + coff + (quad << 3)];
        }
#pragma unroll
        for (int cls = 0; cls < 4; cls++) {
            int brow = cls * 32 + wn * 16 + noff;
            f16x8 bf = *(const f16x8*)&bstage[brow * 40 + (quad << 3)];
#pragma unroll
            for (int mt = 0; mt < 2; mt++)
                acc[mt][cls] = __builtin_amdgcn_mfma_f32_16x16x32_f16(a[mt], bf, acc[mt][cls], 0, 0, 0);
        }
    }

    // ---- epilogue: z = acc + zx; gates; c/h update (bias already in zx) ----
    int fch = nhalf * 32 + wn * 16 + noff;  // f-channel in [0,64)
    const f16* zxp = zx + (size_t)(bb * TT + t) * (HH * WW) * GG;
#pragma unroll
    for (int mt = 0; mt < 2; mt++) {
#pragma unroll
        for (int r = 0; r < 4; r++) {
            int m = wm * 32 + mt * 16 + (quad << 2) + r;
            int y = ty * 8 + (m >> 3), x = tx * 8 + (m & 7);
            size_t p = (size_t)(bb * HH + y) * WW + x;
            size_t zo = (size_t)(y * WW + x) * GG + fch;
            float zi = acc[mt][0][r] + (float)zxp[zo];
            float zf = acc[mt][1][r] + (float)zxp[zo + 64];
            float zc = acc[mt][2][r] + (float)zxp[zo + 128];
            float zzo = acc[mt][3][r] + (float)zxp[zo + 192];
            float ig = hsig(zi), fg = hsig(zf), og = hsig(zzo);
            float cold = cst[p * FF + fch];
            float cn = fg * cold + ig * tanh_fast(zc);
            cst[p * FF + fch] = cn;
            hnew[p * FF + fch] = (f16)(og * tanh_fast(cn));
        }
    }
}

// ---------------- MaxPool 2x2 over h history -> fp32 out ----------------
__global__ void pool_kernel(const f16* __restrict__ hs, float* __restrict__ out) {
    int idx = blockIdx.x * 256 + threadIdx.x;  // < 4,194,304
    int f = idx & 63;
    int ox = (idx >> 6) & 31;
    int oy = (idx >> 11) & 31;
    int t = (idx >> 16) & 15;
    int bb = idx >> 20;
    const f16* base = hs + (size_t)(t + 1) * (BB * HH * WW * FF)
                    + ((size_t)(bb * HH + oy * 2) * WW + ox * 2) * FF + f;
    float v0 = (float)base[0];
    float v1 = (float)base[FF];
    float v2 = (float)base[WW * FF];
    float v3 = (float)base[WW * FF + FF];
    out[idx] = fmaxf(fmaxf(v0, v1), fmaxf(v2, v3));
}

extern "C" void kernel_launch(void* const* d_in, const int* in_sizes, int n_in,
                              void* d_out, int out_size, void* d_ws, size_t ws_size,
                              hipStream_t stream) {
    const float* x = (const float*)d_in[0];
    const float* gamma = (const float*)d_in[1];
    const float* beta = (const float*)d_in[2];
    const float* wx = (const float*)d_in[3];
    const float* wh = (const float*)d_in[4];
    const float* bs = (const float*)d_in[5];
    float* out = (float*)d_out;

    // workspace layout (all 16B-aligned); total ~191.3 MB of 256 MiB
    char* ws = (char*)d_ws;
    f16* xn = (f16*)ws;                       // 16,777,216 B
    f16* wxt = (f16*)(ws + 16777216);         //    147,456 B
    f16* wht = (f16*)(ws + 16924672);         //    294,912 B
    float* cst = (float*)(ws + 17219584);     //  4,194,304 B
    f16* hs = (f16*)(ws + 21413888);          // 17 x 2,097,152 = 35,651,584 B
    f16* zx = (f16*)(ws + 57065472);          // 134,217,728 B

    hipMemsetAsync(cst, 0, (size_t)BB * HH * WW * FF * 4, stream);  // c0 = 0
    hipMemsetAsync(hs, 0, (size_t)BB * HH * WW * FF * 2, stream);   // h0 = 0 (slot 0)

    ln_kernel<<<1024, 256, 0, stream>>>(x, gamma, beta, xn);
    wprep_kernel<<<864, 256, 0, stream>>>(wx, wh, wxt, wht);
    zx_kernel<<<8192, 256, 0, stream>>>(xn, wxt, bs, zx);
    for (int t = 0; t < TT; t++)
        step_kernel<<<512, 256, 0, stream>>>(zx, wht, cst, hs, t);
    pool_kernel<<<16384, 256, 0, stream>>>(hs, out);
}

// Round 3
// 307.318 us; speedup vs baseline: 1.5414x; 1.4437x over previous
//
#include <hip/hip_runtime.h>
#include <hip/hip_fp16.h>

typedef _Float16 f16;
typedef _Float16 f16x8 __attribute__((ext_vector_type(8)));
typedef float f32x4 __attribute__((ext_vector_type(4)));

#define BB 4
#define TT 16
#define HH 64
#define WW 64
#define CC 32
#define FF 64
#define GG 256  // 4F gates

__device__ __forceinline__ float hsig(float z) {
    return fminf(fmaxf(0.2f * z + 0.5f, 0.f), 1.f);
}
__device__ __forceinline__ float tanh_fast(float x) {
    return 1.f - 2.f / (__expf(2.f * x) + 1.f);
}

__device__ __forceinline__ void async_copy16(const void* g, void* l) {
    __builtin_amdgcn_global_load_lds(
        (const __attribute__((address_space(1))) unsigned*)g,
        (__attribute__((address_space(3))) unsigned*)l, 16, 0, 0);
}

// ---------------- LayerNorm over C=32: fp32 in -> fp16 out ----------------
__global__ void ln_kernel(const float* __restrict__ x,
                          const float* __restrict__ gamma,
                          const float* __restrict__ beta,
                          f16* __restrict__ xn) {
    __shared__ float sg[CC], sb[CC];
    if (threadIdx.x < CC) sg[threadIdx.x] = gamma[threadIdx.x];
    else if (threadIdx.x < 2 * CC) sb[threadIdx.x - CC] = beta[threadIdx.x - CC];
    __syncthreads();
    int q = blockIdx.x * 256 + threadIdx.x;  // pixel < B*T*H*W = 262144
    const float* xp = x + (size_t)q * CC;
    float v[CC];
    float s = 0.f, s2 = 0.f;
#pragma unroll
    for (int c = 0; c < CC; c += 4) {
        float4 t4 = *(const float4*)(xp + c);
        v[c] = t4.x; v[c + 1] = t4.y; v[c + 2] = t4.z; v[c + 3] = t4.w;
        s += t4.x + t4.y + t4.z + t4.w;
        s2 += t4.x * t4.x + t4.y * t4.y + t4.z * t4.z + t4.w * t4.w;
    }
    float mu = s * (1.f / CC);
    float var = s2 * (1.f / CC) - mu * mu;
    float rs = rsqrtf(var + 1e-3f);
    f16 o[CC];
#pragma unroll
    for (int c = 0; c < CC; c++)
        o[c] = (f16)((v[c] - mu) * rs * sg[c] + sb[c]);
    f16x8* d = (f16x8*)(xn + (size_t)q * CC);
#pragma unroll
    for (int c = 0; c < 4; c++) d[c] = *(f16x8*)&o[c * 8];
}

// --- Weight prep: wcat[n][0..288) = Wx taps, wcat[n][288..864) = Wh taps (k contiguous) ---
__global__ void wprep_kernel(const float* __restrict__ wx, const float* __restrict__ wh,
                             f16* __restrict__ wcat) {
    int e = blockIdx.x * 256 + threadIdx.x;
    if (e < 9 * CC * GG) {                    // 73728: Wx [tap][c][n] -> [n][tap*32+c]
        int n = e & 255, k = e >> 8;
        wcat[n * 864 + k] = (f16)wx[e];
    } else {
        e -= 9 * CC * GG;
        if (e < 9 * FF * GG) {                // 147456: Wh [tap][f][n] -> [n][288 + tap*64+f]
            int n = e & 255, k = e >> 8;
            wcat[n * 864 + 288 + k] = (f16)wh[e];
        }
    }
}

// ---------------- Fused step: z = conv(xn,Wx)+conv(h,Wh)+b; gates; state ----------------
// Grid: 512 = 256 px-tiles x 2 gate-halves. Block: 256 (4 waves) -> 2 blocks/CU (LDS 78KB).
// Wave (wm,wn): 32 px x 64 gates (16 ch x 4 classes). acc[2][4].
// K = 27 chunks of 32 (9 x-conv + 18 h-conv) in 9 phases of 3; weights double-buffered
// via global_load_lds; ONE barrier per phase (prefetch issued after the barrier so the
// compiler's vmcnt(0)-drain at the NEXT barrier is exactly the wait we need).
__global__ __launch_bounds__(256, 2)
void step_kernel(const f16* __restrict__ xn, const f16* __restrict__ wcat,
                 const float* __restrict__ bs,
                 float* __restrict__ cst, f16* __restrict__ hs, int t) {
    __shared__ __align__(16) f16 xpatch[100 * 72];   // 14.4 KB (32ch used, stride 72)
    __shared__ __align__(16) f16 hpatch[100 * 72];   // 14.4 KB
    __shared__ __align__(16) f16 wbuf[2 * 12288];    // 2 x 24 KB: 128 rows x 96 f16/phase

    int tile = blockIdx.x >> 1, nhalf = blockIdx.x & 1;
    int bb = tile >> 6, ty = (tile >> 3) & 7, tx = tile & 7;
    int tid = threadIdx.x;
    int lane = tid & 63, w = tid >> 6;
    int wm = w >> 1, wn = w & 1;
    int quad = lane >> 4, noff = lane & 15;

    // per-lane global weight addresses: wave w covers buffer rows w*32..w*32+31,
    // 6 instrs x 64 lanes x 16B = 6 KB. row<->gate: gate = (row>>5)*64 + nhalf*32 + (row&31)
    const char* gw[6];
#pragma unroll
    for (int i = 0; i < 6; i++) {
        int qq = i * 64 + lane;               // [0,384)
        int row = w * 32 + qq / 12;
        int piece = qq % 12;
        int gate = ((row >> 5) << 6) + (nhalf << 5) + (row & 31);
        gw[i] = (const char*)wcat + (size_t)gate * 1728 + piece * 16;
    }
    // phase-0 prefetch into buffer 0 (issued first: max latency overlap with patch staging)
#pragma unroll
    for (int i = 0; i < 6; i++)
        async_copy16(gw[i], &wbuf[w * 3072 + i * 512]);

    const f16* xslice = xn + (size_t)(bb * TT + t) * (HH * WW) * CC;
    const f16* hprev = hs + (size_t)t * (BB * HH * WW * FF);
    f16* hnew = hs + (size_t)(t + 1) * (BB * HH * WW * FF);

    // patches: 100 px, zero-padded borders; unified stride 72 f16
    if (tid < 200) {
        int pix = tid >> 1, part = tid & 1;
        int py = pix / 10, px = pix % 10;
        int y = ty * 8 - 1 + py, x = tx * 8 - 1 + px;
        bool in = (y >= 0 && y < HH && x >= 0 && x < WW);
        f16x8 z = {0, 0, 0, 0, 0, 0, 0, 0};
        {   // xpatch: 32 ch, 16 per part
            f16x8* d = (f16x8*)&xpatch[pix * 72 + part * 16];
            if (in) {
                const f16x8* s = (const f16x8*)(xslice + ((size_t)y * WW + x) * CC + part * 16);
                d[0] = s[0]; d[1] = s[1];
            } else { d[0] = z; d[1] = z; }
        }
        {   // hpatch: 64 ch, 32 per part
            f16x8* d = (f16x8*)&hpatch[pix * 72 + part * 32];
            if (in) {
                const f16x8* s = (const f16x8*)(hprev + ((size_t)(bb * HH + y) * WW + x) * FF + part * 32);
                d[0] = s[0]; d[1] = s[1]; d[2] = s[2]; d[3] = s[3];
            } else { d[0] = z; d[1] = z; d[2] = z; d[3] = z; }
        }
    }

    int fch = (nhalf << 5) + (wn << 4) + noff;  // f-channel in [0,64)
    float b_i = bs[fch], b_f = bs[64 + fch], b_c = bs[128 + fch], b_o = bs[192 + fch];

    f32x4 acc[2][4];
#pragma unroll
    for (int i = 0; i < 2; i++)
#pragma unroll
        for (int j = 0; j < 4; j++) acc[i][j] = (f32x4){0.f, 0.f, 0.f, 0.f};

    for (int p = 0; p < 9; ++p) {
        __syncthreads();  // drains vmcnt -> buf[p&1] ready; prior reads of buf[(p+1)&1] done
        if (p < 8) {
#pragma unroll
            for (int i = 0; i < 6; i++)
                async_copy16(gw[i] + (p + 1) * 192,
                             &wbuf[((p + 1) & 1) * 12288 + w * 3072 + i * 512]);
        }
        const f16* wb = &wbuf[(p & 1) * 12288];
#pragma unroll
        for (int cw = 0; cw < 3; ++cw) {
            int c = p * 3 + cw;
            bool isx = c < 9;
            int hc = c - 9;
            int tap = isx ? c : (hc >> 1);
            int coff = isx ? 0 : ((hc & 1) << 5);
            const f16* ap = isx ? xpatch : hpatch;
            int dy = tap / 3, dx = tap % 3;
            f16x8 a[2];
#pragma unroll
            for (int mt = 0; mt < 2; mt++) {
                int m = (wm << 5) + (mt << 4) + noff;
                int pp = ((m >> 3) + dy) * 10 + (m & 7) + dx;
                a[mt] = *(const f16x8*)&ap[pp * 72 + coff + (quad << 3)];
            }
#pragma unroll
            for (int cls = 0; cls < 4; cls++) {
                f16x8 bf = *(const f16x8*)&wb[((cls << 5) + (wn << 4) + noff) * 96 + (cw << 5) + (quad << 3)];
                acc[0][cls] = __builtin_amdgcn_mfma_f32_16x16x32_f16(a[0], bf, acc[0][cls], 0, 0, 0);
                acc[1][cls] = __builtin_amdgcn_mfma_f32_16x16x32_f16(a[1], bf, acc[1][cls], 0, 0, 0);
            }
        }
    }

    // ---- epilogue: gates + state update (per-lane register math) ----
#pragma unroll
    for (int mt = 0; mt < 2; mt++) {
#pragma unroll
        for (int r = 0; r < 4; r++) {
            int m = (wm << 5) + (mt << 4) + (quad << 2) + r;  // C/D row = quad*4+reg
            int y = ty * 8 + (m >> 3), x = tx * 8 + (m & 7);
            size_t p = (size_t)(bb * HH + y) * WW + x;
            float zi = acc[mt][0][r] + b_i;
            float zf = acc[mt][1][r] + b_f;
            float zc = acc[mt][2][r] + b_c;
            float zo = acc[mt][3][r] + b_o;
            float ig = hsig(zi), fg = hsig(zf), og = hsig(zo);
            float cold = cst[p * FF + fch];
            float cn = fg * cold + ig * tanh_fast(zc);
            cst[p * FF + fch] = cn;
            hnew[p * FF + fch] = (f16)(og * tanh_fast(cn));
        }
    }
}

// ---------------- MaxPool 2x2 over h history -> fp32 out ----------------
__global__ void pool_kernel(const f16* __restrict__ hs, float* __restrict__ out) {
    int idx = blockIdx.x * 256 + threadIdx.x;  // < 4,194,304
    int f = idx & 63;
    int ox = (idx >> 6) & 31;
    int oy = (idx >> 11) & 31;
    int t = (idx >> 16) & 15;
    int bb = idx >> 20;
    const f16* base = hs + (size_t)(t + 1) * (BB * HH * WW * FF)
                    + ((size_t)(bb * HH + oy * 2) * WW + ox * 2) * FF + f;
    float v0 = (float)base[0];
    float v1 = (float)base[FF];
    float v2 = (float)base[WW * FF];
    float v3 = (float)base[WW * FF + FF];
    out[idx] = fmaxf(fmaxf(v0, v1), fmaxf(v2, v3));
}

extern "C" void kernel_launch(void* const* d_in, const int* in_sizes, int n_in,
                              void* d_out, int out_size, void* d_ws, size_t ws_size,
                              hipStream_t stream) {
    const float* x = (const float*)d_in[0];
    const float* gamma = (const float*)d_in[1];
    const float* beta = (const float*)d_in[2];
    const float* wx = (const float*)d_in[3];
    const float* wh = (const float*)d_in[4];
    const float* bs = (const float*)d_in[5];
    float* out = (float*)d_out;

    // workspace layout (all 16B-aligned); total ~57 MB
    char* ws = (char*)d_ws;
    f16* xn = (f16*)ws;                       // 16,777,216 B
    f16* wcat = (f16*)(ws + 16777216);        //    442,368 B
    float* cst = (float*)(ws + 17219584);     //  4,194,304 B
    f16* hs = (f16*)(ws + 21413888);          // 17 x 2,097,152 = 35,651,584 B

    hipMemsetAsync(cst, 0, (size_t)BB * HH * WW * FF * 4, stream);  // c0 = 0
    hipMemsetAsync(hs, 0, (size_t)BB * HH * WW * FF * 2, stream);   // h0 = 0 (slot 0)

    ln_kernel<<<1024, 256, 0, stream>>>(x, gamma, beta, xn);
    wprep_kernel<<<864, 256, 0, stream>>>(wx, wh, wcat);
    for (int t = 0; t < TT; t++)
        step_kernel<<<512, 256, 0, stream>>>(xn, wcat, bs, cst, hs, t);
    pool_kernel<<<16384, 256, 0, stream>>>(hs, out);
}